// Round 3
// baseline (157.967 us; speedup 1.0000x reference)
//
#include <hip/hip_runtime.h>

// LearnableTD reverse affine suffix scan, v4.
// v3 post-mortem: three structures (512x4 / 256x8 / pipelined 4-rows)
// all saturate at ~2.5 TB/s HBM; halving concurrency with prefetch
// changed nothing -> memory-system-bound, not latency-bound.
// v4 lever: TRAFFIC, not concurrency.
//   - Outputs are write-once, never re-read: nontemporal stores keep the
//     66 MB/iter output stream from evicting the 100 MB input set out of
//     the 256 MB Infinity Cache. Predicted: FETCH 50 MB -> ~10 MB,
//     inputs become L3-resident across graph iterations.
//   - lam_precompute folded in (8 sigmoids/thread vs 12%-busy VALU is
//     free; drops one dispatch + the lam_arr workspace round-trip).
//
// Affine maps, composed left-over-right ((L∘R).a = L.a + L.b*R.a):
//   b_t   = g*(1-d_t)*l_t
//   lam_t = [r_t + g*(1-d_t)*(1-l_t)*v_{t+1}] + b_t * lam_{t+1}
//   sum_t = [r_t]                             + b_t * sum_{t+1}

#define TPB 256
#define EPT 8
#define NW  (TPB / 64)

struct Aff { float aL, aS, b; };

__device__ inline Aff compose(const Aff& L, const Aff& R) {
    Aff o;
    o.aL = fmaf(L.b, R.aL, L.aL);
    o.aS = fmaf(L.b, R.aS, L.aS);
    o.b  = L.b * R.b;
    return o;
}

typedef float f4a __attribute__((ext_vector_type(4)));              // 16B-aligned
typedef float f4u __attribute__((ext_vector_type(4), aligned(4)));  // 4B-aligned

__global__ __launch_bounds__(TPB, 6)
void td_scan_kernel(const float* __restrict__ values,     // B x (T+1)
                    const float* __restrict__ rewards,    // B x T
                    const float* __restrict__ dones,      // B x T
                    const float* __restrict__ raw_gamma,  // 1
                    const float* __restrict__ raw_lambd,  // >= start+T
                    const int*  __restrict__ start_p,     // 1
                    float* __restrict__ out,              // B*(T+1) lam ++ B*T sum
                    int B, int T)
{
    const int b    = blockIdx.x;
    const int tid  = threadIdx.x;
    const int lane = tid & 63;
    const int wave = tid >> 6;

    __shared__ float s_wAL[NW], s_wAS[NW], s_wB[NW];
    __shared__ float s_vT;

    const float g  = 0.98f + 0.02f / (1.0f + __expf(-raw_gamma[0]));
    const int   s0 = start_p[0];

    const float* vrow = values  + (size_t)b * (T + 1);
    const float* rrow = rewards + (size_t)b * T;
    const float* drow = dones   + (size_t)b * T;
    float* lam_out = out + (size_t)b * (T + 1);
    float* sum_out = out + (size_t)B * (T + 1) + (size_t)b * T;

    const int base = tid * EPT;
    const bool full = (base + EPT) <= T;

    // ---- all loads issued upfront ----
    float r[EPT], d[EPT], l[EPT], vn[EPT];
    if (full) {
        const f4a r0 = *(const f4a*)(rrow + base);
        const f4a r1 = *(const f4a*)(rrow + base + 4);
        const f4a d0 = *(const f4a*)(drow + base);
        const f4a d1 = *(const f4a*)(drow + base + 4);
        const f4u w0 = *(const f4u*)(raw_lambd + s0 + base);      // s0 unknown align
        const f4u w1 = *(const f4u*)(raw_lambd + s0 + base + 4);
        const f4u v0 = *(const f4u*)(vrow + base + 1);            // odd-stride rows
        const f4u v1 = *(const f4u*)(vrow + base + 5);
        r[0]=r0[0]; r[1]=r0[1]; r[2]=r0[2]; r[3]=r0[3];
        r[4]=r1[0]; r[5]=r1[1]; r[6]=r1[2]; r[7]=r1[3];
        d[0]=d0[0]; d[1]=d0[1]; d[2]=d0[2]; d[3]=d0[3];
        d[4]=d1[0]; d[5]=d1[1]; d[6]=d1[2]; d[7]=d1[3];
        l[0]=w0[0]; l[1]=w0[1]; l[2]=w0[2]; l[3]=w0[3];
        l[4]=w1[0]; l[5]=w1[1]; l[6]=w1[2]; l[7]=w1[3];
        vn[0]=v0[0]; vn[1]=v0[1]; vn[2]=v0[2]; vn[3]=v0[3];
        vn[4]=v1[0]; vn[5]=v1[1]; vn[6]=v1[2]; vn[7]=v1[3];
    } else {
        #pragma unroll
        for (int k = 0; k < EPT; ++k) {
            const int t = base + k;
            r[k]  = (t < T) ? rrow[t]            : 0.0f;
            d[k]  = (t < T) ? drow[t]            : 1.0f;
            l[k]  = (t < T) ? raw_lambd[s0 + t]  : 0.0f;
            vn[k] = (t < T) ? vrow[t + 1]        : 0.0f;
        }
    }
    // lambda[t] = 0.9 + 0.1*sigmoid(raw_lambd[start+t])
    #pragma unroll
    for (int k = 0; k < EPT; ++k)
        l[k] = 0.9f + 0.1f / (1.0f + __expf(-l[k]));

    if (tid == 0) {
        const float vT = vrow[T];
        s_vT = vT;
        __builtin_nontemporal_store(vT, lam_out + T);
    }

    // ---- per-thread affine maps + serial composite ----
    Aff M[EPT];
    #pragma unroll
    for (int k = 0; k < EPT; ++k) {
        const int t = base + k;
        if (t < T) {
            const float cont = g * (1.0f - d[k]);
            M[k].b  = cont * l[k];
            M[k].aL = fmaf(cont * (1.0f - l[k]), vn[k], r[k]);
            M[k].aS = r[k];
        } else {
            M[k].aL = 0.0f; M[k].aS = 0.0f; M[k].b = 1.0f;  // identity
        }
    }
    Aff C = M[EPT - 1];
    #pragma unroll
    for (int k = EPT - 2; k >= 0; --k) C = compose(M[k], C);

    // ---- inclusive suffix scan across the wave ----
    Aff S = C;
    #pragma unroll
    for (int dlt = 1; dlt < 64; dlt <<= 1) {
        Aff oth;
        oth.aL = __shfl_down(S.aL, dlt, 64);
        oth.aS = __shfl_down(S.aS, dlt, 64);
        oth.b  = __shfl_down(S.b,  dlt, 64);
        if (lane + dlt < 64) S = compose(S, oth);
    }
    // exclusive suffix (maps strictly right of this thread, within wave)
    Aff E;
    E.aL = __shfl_down(S.aL, 1, 64);
    E.aS = __shfl_down(S.aS, 1, 64);
    E.b  = __shfl_down(S.b,  1, 64);
    if (lane == 63) { E.aL = 0.0f; E.aS = 0.0f; E.b = 1.0f; }

    if (lane == 0) { s_wAL[wave] = S.aL; s_wAS[wave] = S.aS; s_wB[wave] = S.b; }
    __syncthreads();   // the only block-wide barrier

    // ---- cross-wave carry: every thread composes the <=3 aggregates
    //      to its right (wave-uniform, broadcast LDS reads) ----
    float cL = s_vT, cS = 0.0f;
    #pragma unroll
    for (int w = NW - 1; w >= 1; --w) {
        if (w > wave) {
            const float wb = s_wB[w];
            cL = fmaf(wb, cL, s_wAL[w]);
            cS = fmaf(wb, cS, s_wAS[w]);
        }
    }

    // carry at this thread's right boundary
    float xL = fmaf(E.b, cL, E.aL);
    float xS = fmaf(E.b, cS, E.aS);

    // ---- apply through this thread's 8 elements, right-to-left ----
    float oL[EPT], oS[EPT];
    #pragma unroll
    for (int k = EPT - 1; k >= 0; --k) {
        xL = fmaf(M[k].b, xL, M[k].aL);
        xS = fmaf(M[k].b, xS, M[k].aS);
        oL[k] = xL; oS[k] = xS;
    }

    // ---- nontemporal stores: outputs are never re-read; keep them from
    //      evicting the input set out of L3 ----
    if (full) {
        f4a sa, sb;
        sa[0]=oS[0]; sa[1]=oS[1]; sa[2]=oS[2]; sa[3]=oS[3];
        sb[0]=oS[4]; sb[1]=oS[5]; sb[2]=oS[6]; sb[3]=oS[7];
        __builtin_nontemporal_store(sa, (f4a*)(sum_out + base));
        __builtin_nontemporal_store(sb, (f4a*)(sum_out + base + 4));
        f4u la, lb;
        la[0]=oL[0]; la[1]=oL[1]; la[2]=oL[2]; la[3]=oL[3];
        lb[0]=oL[4]; lb[1]=oL[5]; lb[2]=oL[6]; lb[3]=oL[7];
        __builtin_nontemporal_store(la, (f4u*)(lam_out + base));
        __builtin_nontemporal_store(lb, (f4u*)(lam_out + base + 4));
    } else {
        #pragma unroll
        for (int k = 0; k < EPT; ++k) {
            const int t = base + k;
            if (t < T) {
                __builtin_nontemporal_store(oL[k], lam_out + t);
                __builtin_nontemporal_store(oS[k], sum_out + t);
            }
        }
    }
}

extern "C" void kernel_launch(void* const* d_in, const int* in_sizes, int n_in,
                              void* d_out, int out_size, void* d_ws, size_t ws_size,
                              hipStream_t stream) {
    const float* values    = (const float*)d_in[0];
    const float* rewards   = (const float*)d_in[1];
    const float* dones     = (const float*)d_in[2];
    const float* raw_gamma = (const float*)d_in[3];
    const float* raw_lambd = (const float*)d_in[4];
    const int*   start_idx = (const int*)d_in[5];
    float* out = (float*)d_out;

    const int n_values  = in_sizes[0];   // B*(T+1)
    const int n_rewards = in_sizes[1];   // B*T
    const int B = n_values - n_rewards;
    const int T = n_rewards / B;

    td_scan_kernel<<<B, TPB, 0, stream>>>(values, rewards, dones, raw_gamma,
                                          raw_lambd, start_idx, out, B, T);
}

// Round 4
// 154.542 us; speedup vs baseline: 1.0222x; 1.0222x over previous
//
#include <hip/hip_runtime.h>

// LearnableTD reverse affine suffix scan, v5.
// v4 post-mortem: nontemporal stores did NOT move FETCH (49.7 MB both) and
// inflated WRITE by +8 MB (unmerged partial lines on the 4B-misaligned
// lam_out rows) -> +3.2 us at the fixed ~2.5 TB/s pattern rate. Revert NT.
// Keep the lam_precompute fusion (one dispatch, no workspace round-trip).
//
// Evidence that ~2.5 TB/s is the context roofline: three structures
// (512x4 / 256x8 / pipelined-4-rows at HALF the occupancy) all sustain the
// same rate (saturation, not latency); per-direction profiling passes show
// neither direction near its solo ceiling; and the harness's own re-poison
// bulk ops run at the same ~2-2.5 TB/s. Traffic is within ~2% of ideal.
//
// Affine maps, composed left-over-right ((L∘R).a = L.a + L.b*R.a):
//   b_t   = g*(1-d_t)*l_t
//   lam_t = [r_t + g*(1-d_t)*(1-l_t)*v_{t+1}] + b_t * lam_{t+1}
//   sum_t = [r_t]                             + b_t * sum_{t+1}

#define TPB 256
#define EPT 8
#define NW  (TPB / 64)

struct Aff { float aL, aS, b; };

__device__ inline Aff compose(const Aff& L, const Aff& R) {
    Aff o;
    o.aL = fmaf(L.b, R.aL, L.aL);
    o.aS = fmaf(L.b, R.aS, L.aS);
    o.b  = L.b * R.b;
    return o;
}

typedef float f4a __attribute__((ext_vector_type(4)));              // 16B-aligned
typedef float f4u __attribute__((ext_vector_type(4), aligned(4)));  // 4B-aligned

__global__ __launch_bounds__(TPB, 6)
void td_scan_kernel(const float* __restrict__ values,     // B x (T+1)
                    const float* __restrict__ rewards,    // B x T
                    const float* __restrict__ dones,      // B x T
                    const float* __restrict__ raw_gamma,  // 1
                    const float* __restrict__ raw_lambd,  // >= start+T
                    const int*  __restrict__ start_p,     // 1
                    float* __restrict__ out,              // B*(T+1) lam ++ B*T sum
                    int B, int T)
{
    const int b    = blockIdx.x;
    const int tid  = threadIdx.x;
    const int lane = tid & 63;
    const int wave = tid >> 6;

    __shared__ float s_wAL[NW], s_wAS[NW], s_wB[NW];
    __shared__ float s_vT;

    const float g  = 0.98f + 0.02f / (1.0f + __expf(-raw_gamma[0]));
    const int   s0 = start_p[0];

    const float* vrow = values  + (size_t)b * (T + 1);
    const float* rrow = rewards + (size_t)b * T;
    const float* drow = dones   + (size_t)b * T;
    float* lam_out = out + (size_t)b * (T + 1);
    float* sum_out = out + (size_t)B * (T + 1) + (size_t)b * T;

    const int base = tid * EPT;
    const bool full = (base + EPT) <= T;

    // ---- all loads issued upfront ----
    float r[EPT], d[EPT], l[EPT], vn[EPT];
    if (full) {
        const f4a r0 = *(const f4a*)(rrow + base);
        const f4a r1 = *(const f4a*)(rrow + base + 4);
        const f4a d0 = *(const f4a*)(drow + base);
        const f4a d1 = *(const f4a*)(drow + base + 4);
        const f4u w0 = *(const f4u*)(raw_lambd + s0 + base);      // s0 unknown align
        const f4u w1 = *(const f4u*)(raw_lambd + s0 + base + 4);
        const f4u v0 = *(const f4u*)(vrow + base + 1);            // odd-stride rows
        const f4u v1 = *(const f4u*)(vrow + base + 5);
        r[0]=r0[0]; r[1]=r0[1]; r[2]=r0[2]; r[3]=r0[3];
        r[4]=r1[0]; r[5]=r1[1]; r[6]=r1[2]; r[7]=r1[3];
        d[0]=d0[0]; d[1]=d0[1]; d[2]=d0[2]; d[3]=d0[3];
        d[4]=d1[0]; d[5]=d1[1]; d[6]=d1[2]; d[7]=d1[3];
        l[0]=w0[0]; l[1]=w0[1]; l[2]=w0[2]; l[3]=w0[3];
        l[4]=w1[0]; l[5]=w1[1]; l[6]=w1[2]; l[7]=w1[3];
        vn[0]=v0[0]; vn[1]=v0[1]; vn[2]=v0[2]; vn[3]=v0[3];
        vn[4]=v1[0]; vn[5]=v1[1]; vn[6]=v1[2]; vn[7]=v1[3];
    } else {
        #pragma unroll
        for (int k = 0; k < EPT; ++k) {
            const int t = base + k;
            r[k]  = (t < T) ? rrow[t]            : 0.0f;
            d[k]  = (t < T) ? drow[t]            : 1.0f;
            l[k]  = (t < T) ? raw_lambd[s0 + t]  : 0.0f;
            vn[k] = (t < T) ? vrow[t + 1]        : 0.0f;
        }
    }
    // lambda[t] = 0.9 + 0.1*sigmoid(raw_lambd[start+t])
    #pragma unroll
    for (int k = 0; k < EPT; ++k)
        l[k] = 0.9f + 0.1f / (1.0f + __expf(-l[k]));

    if (tid == 0) {
        const float vT = vrow[T];
        s_vT = vT;
        lam_out[T] = vT;
    }

    // ---- per-thread affine maps + serial composite ----
    Aff M[EPT];
    #pragma unroll
    for (int k = 0; k < EPT; ++k) {
        const int t = base + k;
        if (t < T) {
            const float cont = g * (1.0f - d[k]);
            M[k].b  = cont * l[k];
            M[k].aL = fmaf(cont * (1.0f - l[k]), vn[k], r[k]);
            M[k].aS = r[k];
        } else {
            M[k].aL = 0.0f; M[k].aS = 0.0f; M[k].b = 1.0f;  // identity
        }
    }
    Aff C = M[EPT - 1];
    #pragma unroll
    for (int k = EPT - 2; k >= 0; --k) C = compose(M[k], C);

    // ---- inclusive suffix scan across the wave ----
    Aff S = C;
    #pragma unroll
    for (int dlt = 1; dlt < 64; dlt <<= 1) {
        Aff oth;
        oth.aL = __shfl_down(S.aL, dlt, 64);
        oth.aS = __shfl_down(S.aS, dlt, 64);
        oth.b  = __shfl_down(S.b,  dlt, 64);
        if (lane + dlt < 64) S = compose(S, oth);
    }
    // exclusive suffix (maps strictly right of this thread, within wave)
    Aff E;
    E.aL = __shfl_down(S.aL, 1, 64);
    E.aS = __shfl_down(S.aS, 1, 64);
    E.b  = __shfl_down(S.b,  1, 64);
    if (lane == 63) { E.aL = 0.0f; E.aS = 0.0f; E.b = 1.0f; }

    if (lane == 0) { s_wAL[wave] = S.aL; s_wAS[wave] = S.aS; s_wB[wave] = S.b; }
    __syncthreads();   // the only block-wide barrier

    // ---- cross-wave carry: every thread composes the <=3 aggregates
    //      to its right (wave-uniform, broadcast LDS reads) ----
    float cL = s_vT, cS = 0.0f;
    #pragma unroll
    for (int w = NW - 1; w >= 1; --w) {
        if (w > wave) {
            const float wb = s_wB[w];
            cL = fmaf(wb, cL, s_wAL[w]);
            cS = fmaf(wb, cS, s_wAS[w]);
        }
    }

    // carry at this thread's right boundary
    float xL = fmaf(E.b, cL, E.aL);
    float xS = fmaf(E.b, cS, E.aS);

    // ---- apply through this thread's 8 elements, right-to-left ----
    float oL[EPT], oS[EPT];
    #pragma unroll
    for (int k = EPT - 1; k >= 0; --k) {
        xL = fmaf(M[k].b, xL, M[k].aL);
        xS = fmaf(M[k].b, xS, M[k].aS);
        oL[k] = xL; oS[k] = xS;
    }

    // ---- regular cached stores (NT was a measured regression: +8 MB
    //      WRITE from unmerged partial lines on misaligned lam rows) ----
    if (full) {
        f4a sa, sb;
        sa[0]=oS[0]; sa[1]=oS[1]; sa[2]=oS[2]; sa[3]=oS[3];
        sb[0]=oS[4]; sb[1]=oS[5]; sb[2]=oS[6]; sb[3]=oS[7];
        *(f4a*)(sum_out + base)     = sa;
        *(f4a*)(sum_out + base + 4) = sb;
        f4u la, lb;
        la[0]=oL[0]; la[1]=oL[1]; la[2]=oL[2]; la[3]=oL[3];
        lb[0]=oL[4]; lb[1]=oL[5]; lb[2]=oL[6]; lb[3]=oL[7];
        *(f4u*)(lam_out + base)     = la;
        *(f4u*)(lam_out + base + 4) = lb;
    } else {
        #pragma unroll
        for (int k = 0; k < EPT; ++k) {
            const int t = base + k;
            if (t < T) { lam_out[t] = oL[k]; sum_out[t] = oS[k]; }
        }
    }
}

extern "C" void kernel_launch(void* const* d_in, const int* in_sizes, int n_in,
                              void* d_out, int out_size, void* d_ws, size_t ws_size,
                              hipStream_t stream) {
    const float* values    = (const float*)d_in[0];
    const float* rewards   = (const float*)d_in[1];
    const float* dones     = (const float*)d_in[2];
    const float* raw_gamma = (const float*)d_in[3];
    const float* raw_lambd = (const float*)d_in[4];
    const int*   start_idx = (const int*)d_in[5];
    float* out = (float*)d_out;

    const int n_values  = in_sizes[0];   // B*(T+1)
    const int n_rewards = in_sizes[1];   // B*T
    const int B = n_values - n_rewards;
    const int T = n_rewards / B;

    td_scan_kernel<<<B, TPB, 0, stream>>>(values, rewards, dones, raw_gamma,
                                          raw_lambd, start_idx, out, B, T);
}